// Round 2
// baseline (137.576 us; speedup 1.0000x reference)
//
#include <hip/hip_runtime.h>
#include <hip/hip_bf16.h>

// DifferentiableRenderer: B=512 rotations; scatter 32^3 voxels into a 40^3
// grid (u16 source-index, 0xFFFF = empty), then alpha-composite along z.
// One block per batch item; grid held in LDS as two z-slabs of depth 20
// (62.5 KB) to stay under the 64 KB static-LDS limit -> 2 blocks/CU -> all
// 512 blocks co-resident (requires VGPR <= 64, so register use is kept lean).
// Per-ray (S, T) carried in registers across the two slabs.
//
// Numerics: coords = fmaf(z,R2c, fmaf(y,R1c, x*R0c)) + 20, clip [0,39],
// trunc -- chosen to mirror XLA's fma-contracted K=3 dot. Empty cells hold
// logit -1e9 in the reference -> sigmoid == 0 exactly in fp32 -> skipping
// them is exact (contributes 0, leaves transmittance unchanged).

#define NBATCH 512
#define G      40          // destination grid dim
#define HALF   20          // z-slab depth
#define CELLS  (G*G*HALF)  // 32000 cells per slab
#define NRAYS  (G*G)       // 1600
#define EMPTY  0xFFFFu

__global__ __launch_bounds__(1024)
void renderer_kernel(const float* __restrict__ Rall,
                     const float* __restrict__ absorb,
                     const float* __restrict__ atten,
                     float* __restrict__ out)
{
    __shared__ uint4 grid4[CELLS / 8];               // 64000 B, 16B aligned
    unsigned short* grid = (unsigned short*)grid4;

    const int b   = blockIdx.x;
    const int tid = threadIdx.x;

    // Rotation matrix for this batch item (9 floats, L1/L2 broadcast)
    const float* R = Rall + b * 9;
    const float r00 = R[0], r01 = R[1], r02 = R[2];
    const float r10 = R[3], r11 = R[4], r12 = R[5];
    const float r20 = R[6], r21 = R[7], r22 = R[8];

    // v = tid + it*1024  =>  i = it, j = (tid>>5)&31, k = tid&31
    const float y = (float)((tid >> 5) & 31) - 16.f;
    const float z = (float)(tid & 31) - 16.f;

    // Per-ray accumulators: thread handles rays tid and tid+1024
    float S0 = 0.f, T0 = 1.f;
    float S1 = 0.f, T1 = 1.f;

    for (int half = 0; half < 2; ++half) {
        const int zlo = half * HALF;

        // --- init slab to empty (uint4-vectorized: 4000 stores total) ---
        const uint4 e = make_uint4(0xFFFFFFFFu, 0xFFFFFFFFu, 0xFFFFFFFFu, 0xFFFFFFFFu);
        for (int c = tid; c < CELLS / 8; c += 1024)
            grid4[c] = e;
        __syncthreads();

        // --- scatter: 32 voxels per thread (i = it; j,k fixed) ---
        for (int it = 0; it < 32; ++it) {
            const float x = (float)it - 16.f;
            // Mirror XLA dot order: fma-accumulate over contracting dim, then +offset
            const float c0 = fmaf(z, r20, fmaf(y, r10, x * r00)) + 20.f;
            const float c1 = fmaf(z, r21, fmaf(y, r11, x * r01)) + 20.f;
            const float c2 = fmaf(z, r22, fmaf(y, r12, x * r02)) + 20.f;
            const int i0 = (int)fminf(fmaxf(c0, 0.f), 39.f);
            const int i1 = (int)fminf(fmaxf(c1, 0.f), 39.f);
            const int i2 = (int)fminf(fmaxf(c2, 0.f), 39.f);
            if (i2 >= zlo && i2 < zlo + HALF) {
                // duplicate indices: racy write = "unspecified winner", matching
                // JAX scatter-set semantics (duplicates carry equal values here)
                grid[(i0 * G + i1) * HALF + (i2 - zlo)] =
                    (unsigned short)(tid + (it << 10));
            }
        }
        __syncthreads();

        // --- march this slab: rays tid and tid+1024 ---
        #pragma unroll
        for (int rr = 0; rr < 2; ++rr) {
            const int ray = tid + rr * 1024;
            if (ray < NRAYS) {
                float Sacc = rr ? S1 : S0;
                float T    = rr ? T1 : T0;
                const int base = ray * HALF;
                for (int zz = 0; zz < HALF; ++zz) {
                    const unsigned short s = grid[base + zz];
                    if (s != (unsigned short)EMPTY) {
                        const float al = absorb[s];
                        const float tl = atten[s];
                        const float a = 1.f / (1.f + expf(-al));
                        const float t = 1.f / (1.f + expf(-tl));
                        Sacc = fmaf(T * t, a, Sacc);
                        T *= (1.f - t);
                    }
                    // empty: sigmoid(-1e9) == 0 exactly -> skip is exact
                }
                if (rr) { S1 = Sacc; T1 = T; } else { S0 = Sacc; T0 = T; }
            }
        }
        __syncthreads();   // protect grid before next slab's init
    }

    // --- write output [B,40,40,1]: out[b*1600 + i0*40 + i1] ---
    if (tid < NRAYS)        out[b * NRAYS + tid]        = S0;
    if (tid + 1024 < NRAYS) out[b * NRAYS + tid + 1024] = S1;
}

extern "C" void kernel_launch(void* const* d_in, const int* in_sizes, int n_in,
                              void* d_out, int out_size, void* d_ws, size_t ws_size,
                              hipStream_t stream) {
    const float* camera_R    = (const float*)d_in[0];  // [512,3,3]
    const float* absorbance  = (const float*)d_in[1];  // [32,32,32,1]
    const float* attenuation = (const float*)d_in[2];  // [32,32,32,1]
    float* out = (float*)d_out;                        // [512,40,40,1]

    renderer_kernel<<<NBATCH, 1024, 0, stream>>>(camera_R, absorbance, attenuation, out);
}

// Round 3
// 95.713 us; speedup vs baseline: 1.4374x; 1.4374x over previous
//
#include <hip/hip_runtime.h>
#include <hip/hip_bf16.h>

// DifferentiableRenderer: B=512 rotations; scatter 32^3 voxels into a 40^3
// grid (u16 source-index, 0xFFFF = empty), then alpha-composite along z.
//
// R3 changes vs R2 (88 us, VALU-bound):
//  - prep_kernel hoists the per-voxel sigmoids (bit-identical fp32 exprs)
//    into a (NVOX+1) float2 table in d_ws; sentinel row {0,0} makes the
//    march branchless (empty cell: S += T*0*0, T *= 1-0 -- exact).
//  - full 40^3 grid in 125 KiB dynamic LDS (single init/scatter/march pass);
//    fallback to the proven two-slab static-LDS kernel if >64KB opt-in fails.
//  - z-major grid layout: march reads are lane-consecutive u16 (conflict-free).
// Scatter numerics are untouched: c = fmaf(z,R2c, fmaf(y,R1c, x*R0c)) + 20,
// clip [0,39], trunc (absmax was 0.0 with this ordering).

#define NBATCH 512
#define G      40
#define NRAYS  (G*G)        // 1600
#define NCELL  (G*G*G)      // 64000 cells (u16) = 128000 B
#define HALF   20
#define SCELL  (G*G*HALF)   // 32000 cells per slab = 64000 B
#define NVOX   32768
#define EMPTY  0xFFFFu

// ---------- prep: per-voxel sigmoid table + sentinel ----------
__global__ __launch_bounds__(256)
void prep_kernel(const float* __restrict__ ab, const float* __restrict__ at,
                 float2* __restrict__ pre)
{
    const int i = blockIdx.x * 256 + threadIdx.x;
    if (i < NVOX) {
        pre[i] = make_float2(1.f / (1.f + expf(-ab[i])),
                             1.f / (1.f + expf(-at[i])));
    } else if (i == NVOX) {
        pre[i] = make_float2(0.f, 0.f);   // sentinel: contributes nothing, exactly
    }
}

// ---------- full-grid kernel (125 KiB dynamic LDS, 1 block/CU) ----------
template<bool USE_PRE>
__global__ __launch_bounds__(1024, 4)
void render_full(const float* __restrict__ Rall,
                 const float2* __restrict__ pre,
                 const float* __restrict__ ab,
                 const float* __restrict__ at,
                 float* __restrict__ out)
{
    extern __shared__ unsigned short grid[];   // [z][ray] z-major, 64000 cells

    const int b   = blockIdx.x;
    const int tid = threadIdx.x;

    const float* R = Rall + b * 9;
    const float r00 = R[0], r01 = R[1], r02 = R[2];
    const float r10 = R[3], r11 = R[4], r12 = R[5];
    const float r20 = R[6], r21 = R[7], r22 = R[8];

    // v = tid + it*1024  =>  i = it, j = (tid>>5)&31, k = tid&31
    const float y = (float)((tid >> 5) & 31) - 16.f;
    const float z = (float)(tid & 31) - 16.f;

    // --- init grid to empty (8000 uint4 stores) ---
    uint4* g4 = (uint4*)grid;
    const uint4 e = make_uint4(~0u, ~0u, ~0u, ~0u);
    for (int c = tid; c < NCELL / 8; c += 1024)
        g4[c] = e;
    __syncthreads();

    // --- scatter: 32 voxels/thread, branchless (all z valid) ---
    for (int it = 0; it < 32; ++it) {
        const float x = (float)it - 16.f;
        const float c0 = fmaf(z, r20, fmaf(y, r10, x * r00)) + 20.f;
        const float c1 = fmaf(z, r21, fmaf(y, r11, x * r01)) + 20.f;
        const float c2 = fmaf(z, r22, fmaf(y, r12, x * r02)) + 20.f;
        const int i0 = (int)fminf(fmaxf(c0, 0.f), 39.f);
        const int i1 = (int)fminf(fmaxf(c1, 0.f), 39.f);
        const int i2 = (int)fminf(fmaxf(c2, 0.f), 39.f);
        // duplicate cells: racy write = unspecified winner (JAX scatter-set)
        grid[i2 * NRAYS + i0 * G + i1] = (unsigned short)(tid + (it << 10));
    }
    __syncthreads();

    // --- march: ray0 = tid (always), ray1 = tid+1024 (tid<576) ---
    const int  ray0 = tid;
    const int  ray1 = tid + 1024;
    const bool has1 = (ray1 < NRAYS);   // wave-uniform (wave 9 boundary at 576 is clean)

    float S0 = 0.f, T0 = 1.f, S1 = 0.f, T1 = 1.f;

    #pragma unroll 4
    for (int zz = 0; zz < G; ++zz) {
        const int base = zz * NRAYS;
        if (USE_PRE) {
            const int idx0 = min((int)grid[base + ray0], NVOX);
            const float2 p0 = pre[idx0];
            S0 = fmaf(T0 * p0.y, p0.x, S0);
            T0 *= (1.f - p0.y);
            if (has1) {
                const int idx1 = min((int)grid[base + ray1], NVOX);
                const float2 p1 = pre[idx1];
                S1 = fmaf(T1 * p1.y, p1.x, S1);
                T1 *= (1.f - p1.y);
            }
        } else {
            const unsigned short s0 = grid[base + ray0];
            if (s0 != (unsigned short)EMPTY) {
                const float a = 1.f / (1.f + expf(-ab[s0]));
                const float t = 1.f / (1.f + expf(-at[s0]));
                S0 = fmaf(T0 * t, a, S0);
                T0 *= (1.f - t);
            }
            if (has1) {
                const unsigned short s1 = grid[base + ray1];
                if (s1 != (unsigned short)EMPTY) {
                    const float a = 1.f / (1.f + expf(-ab[s1]));
                    const float t = 1.f / (1.f + expf(-at[s1]));
                    S1 = fmaf(T1 * t, a, S1);
                    T1 *= (1.f - t);
                }
            }
        }
    }

    out[b * NRAYS + ray0] = S0;
    if (has1) out[b * NRAYS + ray1] = S1;
}

// ---------- fallback: two-slab kernel, 62.5 KiB static LDS ----------
template<bool USE_PRE>
__global__ __launch_bounds__(1024)
void render_slab(const float* __restrict__ Rall,
                 const float2* __restrict__ pre,
                 const float* __restrict__ ab,
                 const float* __restrict__ at,
                 float* __restrict__ out)
{
    __shared__ uint4 grid4[SCELL / 8];             // 64000 B
    unsigned short* grid = (unsigned short*)grid4; // [z-zlo][ray] z-major

    const int b   = blockIdx.x;
    const int tid = threadIdx.x;

    const float* R = Rall + b * 9;
    const float r00 = R[0], r01 = R[1], r02 = R[2];
    const float r10 = R[3], r11 = R[4], r12 = R[5];
    const float r20 = R[6], r21 = R[7], r22 = R[8];

    const float y = (float)((tid >> 5) & 31) - 16.f;
    const float z = (float)(tid & 31) - 16.f;

    const int  ray0 = tid;
    const int  ray1 = tid + 1024;
    const bool has1 = (ray1 < NRAYS);

    float S0 = 0.f, T0 = 1.f, S1 = 0.f, T1 = 1.f;

    for (int half = 0; half < 2; ++half) {
        const int zlo = half * HALF;

        const uint4 e = make_uint4(~0u, ~0u, ~0u, ~0u);
        for (int c = tid; c < SCELL / 8; c += 1024)
            grid4[c] = e;
        __syncthreads();

        for (int it = 0; it < 32; ++it) {
            const float x = (float)it - 16.f;
            const float c0 = fmaf(z, r20, fmaf(y, r10, x * r00)) + 20.f;
            const float c1 = fmaf(z, r21, fmaf(y, r11, x * r01)) + 20.f;
            const float c2 = fmaf(z, r22, fmaf(y, r12, x * r02)) + 20.f;
            const int i0 = (int)fminf(fmaxf(c0, 0.f), 39.f);
            const int i1 = (int)fminf(fmaxf(c1, 0.f), 39.f);
            const int i2 = (int)fminf(fmaxf(c2, 0.f), 39.f);
            if (i2 >= zlo && i2 < zlo + HALF)
                grid[(i2 - zlo) * NRAYS + i0 * G + i1] =
                    (unsigned short)(tid + (it << 10));
        }
        __syncthreads();

        #pragma unroll 4
        for (int zz = 0; zz < HALF; ++zz) {
            const int base = zz * NRAYS;
            if (USE_PRE) {
                const int idx0 = min((int)grid[base + ray0], NVOX);
                const float2 p0 = pre[idx0];
                S0 = fmaf(T0 * p0.y, p0.x, S0);
                T0 *= (1.f - p0.y);
                if (has1) {
                    const int idx1 = min((int)grid[base + ray1], NVOX);
                    const float2 p1 = pre[idx1];
                    S1 = fmaf(T1 * p1.y, p1.x, S1);
                    T1 *= (1.f - p1.y);
                }
            } else {
                const unsigned short s0 = grid[base + ray0];
                if (s0 != (unsigned short)EMPTY) {
                    const float a = 1.f / (1.f + expf(-ab[s0]));
                    const float t = 1.f / (1.f + expf(-at[s0]));
                    S0 = fmaf(T0 * t, a, S0);
                    T0 *= (1.f - t);
                }
                if (has1) {
                    const unsigned short s1 = grid[base + ray1];
                    if (s1 != (unsigned short)EMPTY) {
                        const float a = 1.f / (1.f + expf(-ab[s1]));
                        const float t = 1.f / (1.f + expf(-at[s1]));
                        S1 = fmaf(T1 * t, a, S1);
                        T1 *= (1.f - t);
                    }
                }
            }
        }
        __syncthreads();
    }

    out[b * NRAYS + ray0] = S0;
    if (has1) out[b * NRAYS + ray1] = S1;
}

extern "C" void kernel_launch(void* const* d_in, const int* in_sizes, int n_in,
                              void* d_out, int out_size, void* d_ws, size_t ws_size,
                              hipStream_t stream)
{
    const float* Rall = (const float*)d_in[0];   // [512,3,3]
    const float* ab   = (const float*)d_in[1];   // [32,32,32,1]
    const float* at   = (const float*)d_in[2];   // [32,32,32,1]
    float*       out  = (float*)d_out;           // [512,40,40,1]
    float2*      pre  = (float2*)d_ws;

    const bool use_pre = ws_size >= (size_t)(NVOX + 1) * sizeof(float2);

    // Opt into >64KB dynamic LDS for the full-grid kernel (gfx950: up to
    // 160 KiB/WG). Not a stream op -- safe under graph capture; idempotent.
    hipError_t e1 = hipFuncSetAttribute(
        reinterpret_cast<const void*>(&render_full<true>),
        hipFuncAttributeMaxDynamicSharedMemorySize, NCELL * 2);
    hipError_t e2 = hipFuncSetAttribute(
        reinterpret_cast<const void*>(&render_full<false>),
        hipFuncAttributeMaxDynamicSharedMemorySize, NCELL * 2);
    const bool big = (e1 == hipSuccess) && (e2 == hipSuccess);

    if (use_pre)
        prep_kernel<<<(NVOX + 256) / 256, 256, 0, stream>>>(ab, at, pre);

    if (big) {
        if (use_pre)
            render_full<true ><<<NBATCH, 1024, NCELL * 2, stream>>>(Rall, pre, ab, at, out);
        else
            render_full<false><<<NBATCH, 1024, NCELL * 2, stream>>>(Rall, pre, ab, at, out);
    } else {
        if (use_pre)
            render_slab<true ><<<NBATCH, 1024, 0, stream>>>(Rall, pre, ab, at, out);
        else
            render_slab<false><<<NBATCH, 1024, 0, stream>>>(Rall, pre, ab, at, out);
    }
}